// Round 1
// baseline (82.695 us; speedup 1.0000x reference)
//
#include <hip/hip_runtime.h>
#include <math.h>

#define BLK 256
#define NX 8            // x-points per thread
#define XT 2            // x-tiles: 4096 / (BLK*NX)
#define NPTS 4096
#define UNITS 65536     // 2 dirs * 8 batches * 4096 points

// Kernel 1: for each (dir, batch, x-tile, y-chunk) block, compute for each of
// its 2048 x-points the min over the y-chunk of ||x-y||^2, using
// dist = 2*( ||x||^2/2 + min_y( ||y||^2/2 - x.y ) ).
// y-chunk staged in LDS as float4 (y0,y1,y2, 0.5*||y||^2); broadcast reads.
__global__ __launch_bounds__(BLK, 2) void chamfer_partial_kernel(
    const float* __restrict__ X, const float* __restrict__ Y,
    float* __restrict__ partial, float* __restrict__ out,
    int C, int ylen)
{
  extern __shared__ float4 sh[];
  int lin = blockIdx.x;
  int c   = lin % C;  lin /= C;
  int xt  = lin % XT; lin /= XT;
  int b   = lin & 7;
  int dir = lin >> 3;

  const float* xs = (dir ? Y : X) + b * (NPTS * 3);
  const float* ys = (dir ? X : Y) + b * (NPTS * 3);

  // Zero d_out once (it is re-poisoned before every launch); kernel 2 runs
  // strictly after this kernel on the stream, so ordering is safe.
  if (partial && blockIdx.x == 0 && threadIdx.x < 8) out[threadIdx.x] = 0.0f;

  // Stage y chunk into LDS.
  int ybase = c * ylen;
  for (int j = threadIdx.x; j < ylen; j += BLK) {
    float y0 = ys[(ybase + j) * 3 + 0];
    float y1 = ys[(ybase + j) * 3 + 1];
    float y2 = ys[(ybase + j) * 3 + 2];
    sh[j] = make_float4(y0, y1, y2, 0.5f * (y0 * y0 + y1 * y1 + y2 * y2));
  }
  __syncthreads();

  // Load this thread's 8 x-points (24 contiguous floats, 16B-aligned).
  int x0i = xt * (BLK * NX) + threadIdx.x * NX;
  float xf[NX * 3];
  {
    const float4* xp = reinterpret_cast<const float4*>(xs + x0i * 3);
    #pragma unroll
    for (int i = 0; i < 6; ++i) {
      float4 p = xp[i];
      xf[i * 4 + 0] = p.x; xf[i * 4 + 1] = p.y;
      xf[i * 4 + 2] = p.z; xf[i * 4 + 3] = p.w;
    }
  }
  float nx0[NX], nx1[NX], nx2[NX], x2h[NX], gmin[NX];
  #pragma unroll
  for (int k = 0; k < NX; ++k) {
    float a = xf[k * 3 + 0], bb = xf[k * 3 + 1], cc = xf[k * 3 + 2];
    nx0[k] = -a; nx1[k] = -bb; nx2[k] = -cc;
    x2h[k] = 0.5f * (a * a + bb * bb + cc * cc);
    gmin[k] = __builtin_inff();
  }

  // Main loop: per y, per x-point: 3 FMA + min (min trees fuse to v_min3).
  for (int j = 0; j < ylen; j += 4) {
    float4 ya = sh[j], yb = sh[j + 1], yc = sh[j + 2], yd = sh[j + 3];
    #pragma unroll
    for (int k = 0; k < NX; ++k) {
      float ga = fmaf(nx0[k], ya.x, fmaf(nx1[k], ya.y, fmaf(nx2[k], ya.z, ya.w)));
      float gb = fmaf(nx0[k], yb.x, fmaf(nx1[k], yb.y, fmaf(nx2[k], yb.z, yb.w)));
      float gc = fmaf(nx0[k], yc.x, fmaf(nx1[k], yc.y, fmaf(nx2[k], yc.z, yc.w)));
      float gd = fmaf(nx0[k], yd.x, fmaf(nx1[k], yd.y, fmaf(nx2[k], yd.z, yd.w)));
      gmin[k] = fminf(fminf(gmin[k], gd), fminf(fminf(ga, gb), gc));
    }
  }

  float res[NX];
  #pragma unroll
  for (int k = 0; k < NX; ++k) res[k] = 2.0f * (x2h[k] + gmin[k]);

  if (partial) {
    // Plain float4 stores of per-chunk partial mins.
    float* dst = partial + (size_t)c * UNITS + dir * 32768 + b * 4096 + x0i;
    float4* d4 = reinterpret_cast<float4*>(dst);
    d4[0] = make_float4(res[0], res[1], res[2], res[3]);
    d4[1] = make_float4(res[4], res[5], res[6], res[7]);
  } else {
    // Direct fallback (no workspace): full min already computed (C==1);
    // block-reduce the sum and atomicAdd into out[b].
    float v = 0.0f;
    #pragma unroll
    for (int k = 0; k < NX; ++k) v += res[k];
    #pragma unroll
    for (int off = 32; off > 0; off >>= 1) v += __shfl_down(v, off, 64);
    __syncthreads();                       // done with sh; reuse for reduction
    float* red = reinterpret_cast<float*>(sh);
    if ((threadIdx.x & 63) == 0) red[threadIdx.x >> 6] = v;
    __syncthreads();
    if (threadIdx.x == 0) {
      float s = red[0] + red[1] + red[2] + red[3];
      atomicAdd(&out[b], s * (1.0f / 4096.0f));
    }
  }
}

// Kernel 2: min across C chunks per x-point, block-reduce sums, one
// atomicAdd per block into out[b]. Grid: 8 batches x 32 slices.
__global__ __launch_bounds__(BLK, 2) void chamfer_reduce_kernel(
    const float* __restrict__ partial, float* __restrict__ out, int C)
{
  int b = blockIdx.x >> 5;
  int s = blockIdx.x & 31;
  int i = s * BLK + threadIdx.x;   // 0..8191 within batch (both directions)
  int dir = i >> 12;
  int xi  = i & 4095;
  int unit = dir * 32768 + b * 4096 + xi;
  float v = partial[unit];
  for (int c = 1; c < C; ++c) v = fminf(v, partial[(size_t)c * UNITS + unit]);
  #pragma unroll
  for (int off = 32; off > 0; off >>= 1) v += __shfl_down(v, off, 64);
  __shared__ float wsum[BLK / 64];
  if ((threadIdx.x & 63) == 0) wsum[threadIdx.x >> 6] = v;
  __syncthreads();
  if (threadIdx.x == 0) {
    float t = wsum[0] + wsum[1] + wsum[2] + wsum[3];
    atomicAdd(&out[b], t * (1.0f / 4096.0f));
  }
}

__global__ void zero_out_kernel(float* out)
{
  if (threadIdx.x < 8) out[threadIdx.x] = 0.0f;
}

extern "C" void kernel_launch(void* const* d_in, const int* in_sizes, int n_in,
                              void* d_out, int out_size, void* d_ws, size_t ws_size,
                              hipStream_t stream)
{
  const float* X = (const float*)d_in[0];
  const float* Y = (const float*)d_in[1];
  float* out = (float*)d_out;

  // Pick y-chunk count so partials fit in workspace (C*UNITS floats).
  int C = 16;
  while (C > 1 && (size_t)C * UNITS * sizeof(float) > ws_size) C >>= 1;
  bool direct = ((size_t)UNITS * sizeof(float) > ws_size);

  if (direct) {
    // Emergency path: no workspace. C==1, full y range per block.
    zero_out_kernel<<<1, 64, 0, stream>>>(out);
    int ylen = NPTS;
    int grid = 2 * 8 * XT;
    chamfer_partial_kernel<<<grid, BLK, ylen * sizeof(float4), stream>>>(
        X, Y, nullptr, out, 1, ylen);
  } else {
    int ylen = NPTS / C;
    int grid = 2 * 8 * XT * C;
    chamfer_partial_kernel<<<grid, BLK, ylen * sizeof(float4), stream>>>(
        X, Y, (float*)d_ws, out, C, ylen);
    chamfer_reduce_kernel<<<256, BLK, 0, stream>>>((const float*)d_ws, out, C);
  }
}